// Round 4
// baseline (2319.381 us; speedup 1.0000x reference)
//
#include <hip/hip_runtime.h>

// FFJORD B=4096 D=64 C=16 H=512, NBIJ=2, NSTEPS=8 RK4 -> 64 sequential MLP+VJP evals.
// Round 10: R8/R9 occupancy hints were ignored; allocator targets 2 blocks/CU because
// 76.5KB LDS admits two -> 8 waves/EU -> 64-VGPR cap -> ~13 regs/thread spilled, scratch
// round-trips serializing every GEMM K-step (~560 cyc/step, MfmaUtil 5.9%). Fix is
// structural: pad LDS past 80KB (kept-alive 8KB dummy) so only ONE block fits per CU;
// max occupancy is then 4 waves/EU and the allocator has no reason to squeeze below the
// 128-VGPR budget. Grid is 256 on 256 CUs, so nothing real is lost.

typedef __attribute__((ext_vector_type(8))) short short8;
typedef __attribute__((ext_vector_type(4))) float f32x4;

#define MFMA_B16(a, b, c) __builtin_amdgcn_mfma_f32_16x16x32_bf16((a), (b), (c), 0, 0, 0)

__device__ __forceinline__ unsigned short f2bf(float f) {
  union { float f; unsigned u; } v; v.f = f;
  return (unsigned short)((v.u + 0x7FFFu + ((v.u >> 16) & 1u)) >> 16);
}
__device__ __forceinline__ float bf2f(unsigned short u) {
  union { unsigned u; float f; } v; v.u = ((unsigned)u) << 16; return v.f;
}
__device__ __forceinline__ float fast_tanh(float x) {
  float e = __expf(2.f * x);
  return 1.f - 2.f * __builtin_amdgcn_rcpf(e + 1.f);
}

// ws layout (ushort units), all bf16 column-major W[n][k]:
// W1f [2][512][96]  @ 0        (k>=81 zero-padded)
// W2f [2][512][512] @ 98304    (W2^T data: forward B)
// W2b [2][512][512] @ 622592   (plain W2: backward B)
// W3f [2][64][512]  @ 1146880  (W3^T: forward B)
// W3b [2][512][64]  @ 1212416  (plain W3: B for e3 = eps@W3^T, used once per bijector)
// W1y [2][64][512]  @ 1277952  (first 64 rows of W1)

__global__ void prep_bf16(const float* __restrict__ W1, const float* __restrict__ W2,
                          const float* __restrict__ W3, unsigned short* __restrict__ ws) {
  int o = blockIdx.x * 256 + threadIdx.x;
  if (o < 98304) {
    int ib = o / 49152, r = o % 49152, n = r / 96, k = r % 96;
    ws[o] = (k < 81) ? f2bf(W1[(size_t)ib * 41472 + k * 512 + n]) : (unsigned short)0;
  } else if (o < 622592) {
    int o2 = o - 98304;
    int ib = o2 / 262144, r = o2 % 262144, n = r / 512, k = r % 512;
    ws[o] = f2bf(W2[(size_t)ib * 262144 + k * 512 + n]);
  } else if (o < 1146880) {
    ws[o] = f2bf(W2[o - 622592]);
  } else if (o < 1212416) {
    int o2 = o - 1146880;
    int ib = o2 / 32768, r = o2 % 32768, n = r / 512, k = r % 512;
    ws[o] = f2bf(W3[(size_t)ib * 32768 + k * 64 + n]);
  } else if (o < 1277952) {
    ws[o] = f2bf(W3[o - 1212416]);
  } else if (o < 1343488) {
    int o2 = o - 1277952;
    int ib = o2 / 32768, r = o2 % 32768, n = r / 512, k = r % 512;
    ws[o] = f2bf(W1[(size_t)ib * 41472 + n * 512 + k]);
  }
}

#define ZS 104   // z A-buffer stride (K=96 used)
#define HS 520   // h buffers stride (K=512)
#define ES 72    // eps stride (K=64)

__global__ __launch_bounds__(1024) void ffjord_mfma(
    const float* __restrict__ x, const float* __restrict__ cond, const float* __restrict__ eps,
    const float* __restrict__ b1g, const float* __restrict__ b2g, const float* __restrict__ b3g,
    const unsigned short* __restrict__ ws, float* __restrict__ out) {
  __shared__ unsigned short zA[16 * ZS];
  __shared__ unsigned short h1A[16 * HS];   // h1; overwritten by g1 in GEMM4b
  __shared__ unsigned short h2A[16 * HS];
  __shared__ unsigned short g2A[16 * HS];
  __shared__ unsigned short epsA[16 * ES];
  __shared__ float eps_s[16][64];
  __shared__ float f_s[16][64];
  __shared__ float ycur[16][64], ytmp[16][64], yacc[16][64];
  __shared__ float l_row[16], ld_row[16], ldacc[16];
  // Occupancy clamp: pushes LDS from 76.5KB to ~84.5KB so a 2nd block cannot fit on a
  // CU (160KB). Kept alive via a never-true guarded read below.
  __shared__ unsigned short occ_pad[4096];

  const int t = threadIdx.x;
  const int wave = t >> 6;
  const int lane = t & 63;
  const int lane15 = lane & 15;
  const int q8 = (lane >> 4) * 8;       // frag k-offset; C/D row base = q8>>1
  const int rowb = q8 >> 1;
  const int row0 = blockIdx.x * 16;
  const int ws32 = wave * 32;           // N-slice base for N=512 GEMMs
  const int nt3 = wave & 3;             // N-tile for N=64 GEMMs (3f, 5b)
  const int kb3 = (wave >> 2) * 128;    // K-slice base for N=64 GEMMs
  const int tm = t >> 6, td = t & 63;   // (row, dim) element owned by this thread

  occ_pad[t & 4095] = (unsigned short)t;

  // one-time init (1024 threads cover 16x64)
  {
    float xv = x[(size_t)(row0 + tm) * 64 + td];
    ycur[tm][td] = xv; ytmp[tm][td] = xv;
  }
  if (t < 512) {
    int m = t >> 5, kk = t & 31;
    zA[m * ZS + 64 + kk] = (kk < 16) ? f2bf(cond[(size_t)(row0 + m) * 16 + kk]) : (unsigned short)0;
  }
  if (t < 16) { ld_row[t] = 0.f; l_row[t] = 0.f; }

  const float dt = 0.125f;
  const float w06 = dt / 6.f, w13 = dt / 3.f;

  for (int ib = 0; ib < 2; ++ib) {
    const unsigned short* W1f = ws + 0       + ib * 49152;
    const unsigned short* W2f = ws + 98304   + ib * 262144;
    const unsigned short* W2b = ws + 622592  + ib * 262144;
    const unsigned short* W3f = ws + 1146880 + ib * 32768;
    const unsigned short* W3b = ws + 1212416 + ib * 32768;
    const unsigned short* W1y = ws + 1277952 + ib * 32768;
    const float* b1b = b1g + ib * 512;
    const float* b2b = b2g + ib * 512;
    const float* b3b = b3g + ib * 64;

    // stage eps
    {
      float ev = eps[((size_t)ib * 4096 + row0 + tm) * 64 + td];
      eps_s[tm][td] = ev;
      epsA[tm * ES + td] = f2bf(ev);
    }
    __syncthreads();

    // ---- e3 = eps @ W3^T (N=512, K=64), ONCE per bijector; kept in registers.
    // Epilogue mapping (n = ws32 + tl*16 + lane15, m = rowb + rg) == GEMM2's mapping.
    float e3r[8];
    {
      f32x4 a0 = {0,0,0,0}, a1 = {0,0,0,0};
      const unsigned short* ap = epsA + lane15 * ES + q8;
      const unsigned short* wp = W3b + (size_t)(ws32 + lane15) * 64 + q8;
      #pragma unroll
      for (int kk = 0; kk < 64; kk += 32) {
        short8 a = *(const short8*)(ap + kk);
        a0 = MFMA_B16(a, *(const short8*)(wp + kk),           a0);
        a1 = MFMA_B16(a, *(const short8*)(wp + 16 * 64 + kk), a1);
      }
      #pragma unroll
      for (int rg = 0; rg < 4; ++rg) { e3r[rg] = a0[rg]; e3r[4 + rg] = a1[rg]; }
    }
    // no barrier needed: epsA is not rewritten until next bijector's staging.

    for (int it = 0; it < 32; ++it) {
      const int s = it & 3;
      const float te = (it >> 2) * dt + ((s == 0) ? 0.f : (s == 3) ? dt : 0.5f * dt);

      // ---- P0: z build + zero f accumulator + deferred logdet stage-update ----
      zA[tm * ZS + td] = f2bf(ytmp[tm][td]);
      f_s[tm][td] = 0.f;
      if (t < 16) {
        if (it > 0) {
          int sp = (it - 1) & 3;
          float lv = l_row[t];
          if (sp == 0)      ldacc[t] = w06 * lv;
          else if (sp < 3)  ldacc[t] += w13 * lv;
          else              ld_row[t] += ldacc[t] + w06 * lv;
        }
        l_row[t] = 0.f;
        zA[t * ZS + 80] = f2bf(te);
      }
      __syncthreads();

      // ---- P1: GEMM1: h1 = tanh(z @ W1 + b1), K=96, N=32/wave ----
      {
        f32x4 a0 = {0,0,0,0}, a1 = {0,0,0,0};
        const unsigned short* ap = zA + lane15 * ZS + q8;
        const unsigned short* wp = W1f + (size_t)(ws32 + lane15) * 96 + q8;
        #pragma unroll
        for (int k0 = 0; k0 < 96; k0 += 32) {
          short8 a = *(const short8*)(ap + k0);
          a0 = MFMA_B16(a, *(const short8*)(wp + k0),           a0);
          a1 = MFMA_B16(a, *(const short8*)(wp + 16 * 96 + k0), a1);
        }
        #pragma unroll
        for (int tl = 0; tl < 2; ++tl) {
          int n = ws32 + tl * 16 + lane15;
          float bias = b1b[n];
          f32x4 ac = tl ? a1 : a0;
          #pragma unroll
          for (int rg = 0; rg < 4; ++rg)
            h1A[(rowb + rg) * HS + n] = f2bf(fast_tanh(ac[rg] + bias));
        }
      }
      __syncthreads();

      // ---- P2: GEMM2: h2 = tanh(h1 @ W2 + b2); g2 = e3*(1-h2^2) fused in epilogue ----
      {
        f32x4 a0 = {0,0,0,0}, a1 = {0,0,0,0};
        const unsigned short* ap = h1A + lane15 * HS + q8;
        const unsigned short* wp = W2f + (size_t)(ws32 + lane15) * 512 + q8;
        #pragma unroll 8
        for (int k0 = 0; k0 < 512; k0 += 32) {
          short8 a = *(const short8*)(ap + k0);
          a0 = MFMA_B16(a, *(const short8*)(wp + k0),            a0);
          a1 = MFMA_B16(a, *(const short8*)(wp + 16 * 512 + k0), a1);
        }
        #pragma unroll
        for (int tl = 0; tl < 2; ++tl) {
          int n = ws32 + tl * 16 + lane15;
          float bias = b2b[n];
          f32x4 ac = tl ? a1 : a0;
          #pragma unroll
          for (int rg = 0; rg < 4; ++rg) {
            float h = fast_tanh(ac[rg] + bias);
            int off = (rowb + rg) * HS + n;
            h2A[off] = f2bf(h);
            g2A[off] = f2bf(e3r[tl * 4 + rg] * (1.f - h * h));
          }
        }
      }
      __syncthreads();

      // ---- P3: GEMM3f (f += h2 @ W3f, (N-tile,K-slice)/wave, atomic reduce)
      //          + GEMM4b (g1 = (g2 @ W2^T)*(1-h1^2) -> h1A in place) ----
      {
        f32x4 c0 = {0,0,0,0};
        const unsigned short* ap3 = h2A + lane15 * HS + kb3 + q8;
        const unsigned short* wp3 = W3f + (size_t)(nt3 * 16 + lane15) * 512 + kb3 + q8;
        #pragma unroll
        for (int kk = 0; kk < 128; kk += 32)
          c0 = MFMA_B16(*(const short8*)(ap3 + kk), *(const short8*)(wp3 + kk), c0);
        #pragma unroll
        for (int rg = 0; rg < 4; ++rg)
          atomicAdd(&f_s[rowb + rg][nt3 * 16 + lane15], c0[rg]);
      }
      {
        f32x4 a0 = {0,0,0,0}, a1 = {0,0,0,0};
        const unsigned short* ap = g2A + lane15 * HS + q8;
        const unsigned short* wp = W2b + (size_t)(ws32 + lane15) * 512 + q8;
        #pragma unroll 8
        for (int k0 = 0; k0 < 512; k0 += 32) {
          short8 a = *(const short8*)(ap + k0);
          a0 = MFMA_B16(a, *(const short8*)(wp + k0),            a0);
          a1 = MFMA_B16(a, *(const short8*)(wp + 16 * 512 + k0), a1);
        }
        #pragma unroll
        for (int tl = 0; tl < 2; ++tl) {
          int n = ws32 + tl * 16 + lane15;
          f32x4 ac = tl ? a1 : a0;
          #pragma unroll
          for (int rg = 0; rg < 4; ++rg) {
            int off = (rowb + rg) * HS + n;
            float h = bf2f(h1A[off]);
            h1A[off] = f2bf(ac[rg] * (1.f - h * h));
          }
        }
      }
      __syncthreads();

      // ---- P4: GEMM5b (gz = g1 @ W1y^T, l = sum(gz*eps)) + RK4 y-update ----
      {
        f32x4 c0 = {0,0,0,0};
        const unsigned short* ap = h1A + lane15 * HS + kb3 + q8;
        const unsigned short* wp = W1y + (size_t)(nt3 * 16 + lane15) * 512 + kb3 + q8;
        #pragma unroll
        for (int kk = 0; kk < 128; kk += 32)
          c0 = MFMA_B16(*(const short8*)(ap + kk), *(const short8*)(wp + kk), c0);
        #pragma unroll
        for (int rg = 0; rg < 4; ++rg) {
          int m = rowb + rg;
          float p = c0[rg] * eps_s[m][nt3 * 16 + lane15];
          #pragma unroll
          for (int o = 1; o < 16; o <<= 1) p += __shfl_xor(p, o);
          if (lane15 == 0) atomicAdd(&l_row[m], p);
        }
      }
      {
        const float wk = (s == 0 || s == 3) ? w06 : w13;
        float fv = f_s[tm][td] + b3b[td];
        if (s == 0)      yacc[tm][td] = ycur[tm][td] + w06 * fv;
        else if (s < 3)  yacc[tm][td] += wk * fv;
        if (s < 3) {
          ytmp[tm][td] = ycur[tm][td] + ((s == 2) ? dt : 0.5f * dt) * fv;
        } else {
          float yn = yacc[tm][td] + w06 * fv;
          ycur[tm][td] = yn; ytmp[tm][td] = yn;
        }
      }
      __syncthreads();
    }

    // finalize deferred logdet stage for it=31 (stage 3)
    if (t < 16) { ld_row[t] += ldacc[t] + w06 * l_row[t]; l_row[t] = 0.f; }
  }

  out[(size_t)(row0 + tm) * 65 + td] = ycur[tm][td];
  if (t < 16) out[(size_t)(row0 + t) * 65 + 64] = ld_row[t];
  // keep occ_pad alive (b3g is never 8 at runtime; compiler can't prove it)
  if (b3g == (const float*)8) out[0] = bf2f(occ_pad[t & 4095]);
}

extern "C" void kernel_launch(void* const* d_in, const int* in_sizes, int n_in,
                              void* d_out, int out_size, void* d_ws, size_t ws_size,
                              hipStream_t stream) {
  (void)in_sizes; (void)n_in; (void)out_size; (void)ws_size;
  const float* x    = (const float*)d_in[0];
  const float* cond = (const float*)d_in[1];
  const float* eps  = (const float*)d_in[2];
  const float* W1   = (const float*)d_in[3];
  const float* b1   = (const float*)d_in[4];
  const float* W2   = (const float*)d_in[5];
  const float* b2   = (const float*)d_in[6];
  const float* W3   = (const float*)d_in[7];
  const float* b3   = (const float*)d_in[8];
  float* out = (float*)d_out;
  unsigned short* ws = (unsigned short*)d_ws;

  const int prep_total = 1343488;
  prep_bf16<<<(prep_total + 255) / 256, 256, 0, stream>>>(W1, W2, W3, ws);
  ffjord_mfma<<<256, 1024, 0, stream>>>(x, cond, eps, b1, b2, b3, ws, out);
}

// Round 5
// 2304.736 us; speedup vs baseline: 1.0064x; 1.0064x over previous
//
#include <hip/hip_runtime.h>

// FFJORD B=4096 D=64 C=16 H=512, NBIJ=2, NSTEPS=8 RK4 -> 64 sequential MLP+VJP evals.
// Round 11: R8-R10 proved the 64-VGPR allocation is NOT occupancy-driven (LDS pad forced
// 1 block/CU, still 64). Model: VGPR_Count=64 is the arch half; accs/e3r sit in AGPRs;
// total is already at the 128/wave budget for 4 waves/EU. unroll-8 dual-B GEMM loops
// demand ~96 load-regs -> ~13 regs/thread spill INSIDE the K-loops; spill/fill chains
// serialize K-steps at L2 latency. Fix: cut demand -> #pragma unroll 4 on GEMM2/GEMM4b
// (8 loads in flight still covers L2 latency); occ_pad removed (proven useless).

typedef __attribute__((ext_vector_type(8))) short short8;
typedef __attribute__((ext_vector_type(4))) float f32x4;

#define MFMA_B16(a, b, c) __builtin_amdgcn_mfma_f32_16x16x32_bf16((a), (b), (c), 0, 0, 0)

__device__ __forceinline__ unsigned short f2bf(float f) {
  union { float f; unsigned u; } v; v.f = f;
  return (unsigned short)((v.u + 0x7FFFu + ((v.u >> 16) & 1u)) >> 16);
}
__device__ __forceinline__ float bf2f(unsigned short u) {
  union { unsigned u; float f; } v; v.u = ((unsigned)u) << 16; return v.f;
}
__device__ __forceinline__ float fast_tanh(float x) {
  float e = __expf(2.f * x);
  return 1.f - 2.f * __builtin_amdgcn_rcpf(e + 1.f);
}

// ws layout (ushort units), all bf16 column-major W[n][k]:
// W1f [2][512][96]  @ 0        (k>=81 zero-padded)
// W2f [2][512][512] @ 98304    (W2^T data: forward B)
// W2b [2][512][512] @ 622592   (plain W2: backward B)
// W3f [2][64][512]  @ 1146880  (W3^T: forward B)
// W3b [2][512][64]  @ 1212416  (plain W3: B for e3 = eps@W3^T, used once per bijector)
// W1y [2][64][512]  @ 1277952  (first 64 rows of W1)

__global__ void prep_bf16(const float* __restrict__ W1, const float* __restrict__ W2,
                          const float* __restrict__ W3, unsigned short* __restrict__ ws) {
  int o = blockIdx.x * 256 + threadIdx.x;
  if (o < 98304) {
    int ib = o / 49152, r = o % 49152, n = r / 96, k = r % 96;
    ws[o] = (k < 81) ? f2bf(W1[(size_t)ib * 41472 + k * 512 + n]) : (unsigned short)0;
  } else if (o < 622592) {
    int o2 = o - 98304;
    int ib = o2 / 262144, r = o2 % 262144, n = r / 512, k = r % 512;
    ws[o] = f2bf(W2[(size_t)ib * 262144 + k * 512 + n]);
  } else if (o < 1146880) {
    ws[o] = f2bf(W2[o - 622592]);
  } else if (o < 1212416) {
    int o2 = o - 1146880;
    int ib = o2 / 32768, r = o2 % 32768, n = r / 512, k = r % 512;
    ws[o] = f2bf(W3[(size_t)ib * 32768 + k * 64 + n]);
  } else if (o < 1277952) {
    ws[o] = f2bf(W3[o - 1212416]);
  } else if (o < 1343488) {
    int o2 = o - 1277952;
    int ib = o2 / 32768, r = o2 % 32768, n = r / 512, k = r % 512;
    ws[o] = f2bf(W1[(size_t)ib * 41472 + n * 512 + k]);
  }
}

#define ZS 104   // z A-buffer stride (K=96 used)
#define HS 520   // h buffers stride (K=512)
#define ES 72    // eps stride (K=64)

__global__ __launch_bounds__(1024) void ffjord_mfma(
    const float* __restrict__ x, const float* __restrict__ cond, const float* __restrict__ eps,
    const float* __restrict__ b1g, const float* __restrict__ b2g, const float* __restrict__ b3g,
    const unsigned short* __restrict__ ws, float* __restrict__ out) {
  __shared__ unsigned short zA[16 * ZS];
  __shared__ unsigned short h1A[16 * HS];   // h1; overwritten by g1 in GEMM4b
  __shared__ unsigned short h2A[16 * HS];
  __shared__ unsigned short g2A[16 * HS];
  __shared__ unsigned short epsA[16 * ES];
  __shared__ float eps_s[16][64];
  __shared__ float f_s[16][64];
  __shared__ float ycur[16][64], ytmp[16][64], yacc[16][64];
  __shared__ float l_row[16], ld_row[16], ldacc[16];

  const int t = threadIdx.x;
  const int wave = t >> 6;
  const int lane = t & 63;
  const int lane15 = lane & 15;
  const int q8 = (lane >> 4) * 8;       // frag k-offset; C/D row base = q8>>1
  const int rowb = q8 >> 1;
  const int row0 = blockIdx.x * 16;
  const int ws32 = wave * 32;           // N-slice base for N=512 GEMMs
  const int nt3 = wave & 3;             // N-tile for N=64 GEMMs (3f, 5b)
  const int kb3 = (wave >> 2) * 128;    // K-slice base for N=64 GEMMs
  const int tm = t >> 6, td = t & 63;   // (row, dim) element owned by this thread

  // one-time init (1024 threads cover 16x64)
  {
    float xv = x[(size_t)(row0 + tm) * 64 + td];
    ycur[tm][td] = xv; ytmp[tm][td] = xv;
  }
  if (t < 512) {
    int m = t >> 5, kk = t & 31;
    zA[m * ZS + 64 + kk] = (kk < 16) ? f2bf(cond[(size_t)(row0 + m) * 16 + kk]) : (unsigned short)0;
  }
  if (t < 16) { ld_row[t] = 0.f; l_row[t] = 0.f; }

  const float dt = 0.125f;
  const float w06 = dt / 6.f, w13 = dt / 3.f;

  for (int ib = 0; ib < 2; ++ib) {
    const unsigned short* W1f = ws + 0       + ib * 49152;
    const unsigned short* W2f = ws + 98304   + ib * 262144;
    const unsigned short* W2b = ws + 622592  + ib * 262144;
    const unsigned short* W3f = ws + 1146880 + ib * 32768;
    const unsigned short* W3b = ws + 1212416 + ib * 32768;
    const unsigned short* W1y = ws + 1277952 + ib * 32768;
    const float* b1b = b1g + ib * 512;
    const float* b2b = b2g + ib * 512;
    const float* b3b = b3g + ib * 64;

    // stage eps
    {
      float ev = eps[((size_t)ib * 4096 + row0 + tm) * 64 + td];
      eps_s[tm][td] = ev;
      epsA[tm * ES + td] = f2bf(ev);
    }
    __syncthreads();

    // ---- e3 = eps @ W3^T (N=512, K=64), ONCE per bijector; kept in registers.
    // Epilogue mapping (n = ws32 + tl*16 + lane15, m = rowb + rg) == GEMM2's mapping.
    float e3r[8];
    {
      f32x4 a0 = {0,0,0,0}, a1 = {0,0,0,0};
      const unsigned short* ap = epsA + lane15 * ES + q8;
      const unsigned short* wp = W3b + (size_t)(ws32 + lane15) * 64 + q8;
      #pragma unroll
      for (int kk = 0; kk < 64; kk += 32) {
        short8 a = *(const short8*)(ap + kk);
        a0 = MFMA_B16(a, *(const short8*)(wp + kk),           a0);
        a1 = MFMA_B16(a, *(const short8*)(wp + 16 * 64 + kk), a1);
      }
      #pragma unroll
      for (int rg = 0; rg < 4; ++rg) { e3r[rg] = a0[rg]; e3r[4 + rg] = a1[rg]; }
    }
    // no barrier needed: epsA is not rewritten until next bijector's staging.

    for (int it = 0; it < 32; ++it) {
      const int s = it & 3;
      const float te = (it >> 2) * dt + ((s == 0) ? 0.f : (s == 3) ? dt : 0.5f * dt);

      // ---- P0: z build + zero f accumulator + deferred logdet stage-update ----
      zA[tm * ZS + td] = f2bf(ytmp[tm][td]);
      f_s[tm][td] = 0.f;
      if (t < 16) {
        if (it > 0) {
          int sp = (it - 1) & 3;
          float lv = l_row[t];
          if (sp == 0)      ldacc[t] = w06 * lv;
          else if (sp < 3)  ldacc[t] += w13 * lv;
          else              ld_row[t] += ldacc[t] + w06 * lv;
        }
        l_row[t] = 0.f;
        zA[t * ZS + 80] = f2bf(te);
      }
      __syncthreads();

      // ---- P1: GEMM1: h1 = tanh(z @ W1 + b1), K=96, N=32/wave ----
      {
        f32x4 a0 = {0,0,0,0}, a1 = {0,0,0,0};
        const unsigned short* ap = zA + lane15 * ZS + q8;
        const unsigned short* wp = W1f + (size_t)(ws32 + lane15) * 96 + q8;
        #pragma unroll
        for (int k0 = 0; k0 < 96; k0 += 32) {
          short8 a = *(const short8*)(ap + k0);
          a0 = MFMA_B16(a, *(const short8*)(wp + k0),           a0);
          a1 = MFMA_B16(a, *(const short8*)(wp + 16 * 96 + k0), a1);
        }
        #pragma unroll
        for (int tl = 0; tl < 2; ++tl) {
          int n = ws32 + tl * 16 + lane15;
          float bias = b1b[n];
          f32x4 ac = tl ? a1 : a0;
          #pragma unroll
          for (int rg = 0; rg < 4; ++rg)
            h1A[(rowb + rg) * HS + n] = f2bf(fast_tanh(ac[rg] + bias));
        }
      }
      __syncthreads();

      // ---- P2: GEMM2: h2 = tanh(h1 @ W2 + b2); g2 = e3*(1-h2^2) fused in epilogue ----
      {
        f32x4 a0 = {0,0,0,0}, a1 = {0,0,0,0};
        const unsigned short* ap = h1A + lane15 * HS + q8;
        const unsigned short* wp = W2f + (size_t)(ws32 + lane15) * 512 + q8;
        #pragma unroll 4
        for (int k0 = 0; k0 < 512; k0 += 32) {
          short8 a = *(const short8*)(ap + k0);
          a0 = MFMA_B16(a, *(const short8*)(wp + k0),            a0);
          a1 = MFMA_B16(a, *(const short8*)(wp + 16 * 512 + k0), a1);
        }
        #pragma unroll
        for (int tl = 0; tl < 2; ++tl) {
          int n = ws32 + tl * 16 + lane15;
          float bias = b2b[n];
          f32x4 ac = tl ? a1 : a0;
          #pragma unroll
          for (int rg = 0; rg < 4; ++rg) {
            float h = fast_tanh(ac[rg] + bias);
            int off = (rowb + rg) * HS + n;
            h2A[off] = f2bf(h);
            g2A[off] = f2bf(e3r[tl * 4 + rg] * (1.f - h * h));
          }
        }
      }
      __syncthreads();

      // ---- P3: GEMM3f (f += h2 @ W3f, (N-tile,K-slice)/wave, atomic reduce)
      //          + GEMM4b (g1 = (g2 @ W2^T)*(1-h1^2) -> h1A in place) ----
      {
        f32x4 c0 = {0,0,0,0};
        const unsigned short* ap3 = h2A + lane15 * HS + kb3 + q8;
        const unsigned short* wp3 = W3f + (size_t)(nt3 * 16 + lane15) * 512 + kb3 + q8;
        #pragma unroll
        for (int kk = 0; kk < 128; kk += 32)
          c0 = MFMA_B16(*(const short8*)(ap3 + kk), *(const short8*)(wp3 + kk), c0);
        #pragma unroll
        for (int rg = 0; rg < 4; ++rg)
          atomicAdd(&f_s[rowb + rg][nt3 * 16 + lane15], c0[rg]);
      }
      {
        f32x4 a0 = {0,0,0,0}, a1 = {0,0,0,0};
        const unsigned short* ap = g2A + lane15 * HS + q8;
        const unsigned short* wp = W2b + (size_t)(ws32 + lane15) * 512 + q8;
        #pragma unroll 4
        for (int k0 = 0; k0 < 512; k0 += 32) {
          short8 a = *(const short8*)(ap + k0);
          a0 = MFMA_B16(a, *(const short8*)(wp + k0),            a0);
          a1 = MFMA_B16(a, *(const short8*)(wp + 16 * 512 + k0), a1);
        }
        #pragma unroll
        for (int tl = 0; tl < 2; ++tl) {
          int n = ws32 + tl * 16 + lane15;
          f32x4 ac = tl ? a1 : a0;
          #pragma unroll
          for (int rg = 0; rg < 4; ++rg) {
            int off = (rowb + rg) * HS + n;
            float h = bf2f(h1A[off]);
            h1A[off] = f2bf(ac[rg] * (1.f - h * h));
          }
        }
      }
      __syncthreads();

      // ---- P4: GEMM5b (gz = g1 @ W1y^T, l = sum(gz*eps)) + RK4 y-update ----
      {
        f32x4 c0 = {0,0,0,0};
        const unsigned short* ap = h1A + lane15 * HS + kb3 + q8;
        const unsigned short* wp = W1y + (size_t)(nt3 * 16 + lane15) * 512 + kb3 + q8;
        #pragma unroll
        for (int kk = 0; kk < 128; kk += 32)
          c0 = MFMA_B16(*(const short8*)(ap + kk), *(const short8*)(wp + kk), c0);
        #pragma unroll
        for (int rg = 0; rg < 4; ++rg) {
          int m = rowb + rg;
          float p = c0[rg] * eps_s[m][nt3 * 16 + lane15];
          #pragma unroll
          for (int o = 1; o < 16; o <<= 1) p += __shfl_xor(p, o);
          if (lane15 == 0) atomicAdd(&l_row[m], p);
        }
      }
      {
        const float wk = (s == 0 || s == 3) ? w06 : w13;
        float fv = f_s[tm][td] + b3b[td];
        if (s == 0)      yacc[tm][td] = ycur[tm][td] + w06 * fv;
        else if (s < 3)  yacc[tm][td] += wk * fv;
        if (s < 3) {
          ytmp[tm][td] = ycur[tm][td] + ((s == 2) ? dt : 0.5f * dt) * fv;
        } else {
          float yn = yacc[tm][td] + w06 * fv;
          ycur[tm][td] = yn; ytmp[tm][td] = yn;
        }
      }
      __syncthreads();
    }

    // finalize deferred logdet stage for it=31 (stage 3)
    if (t < 16) { ld_row[t] += ldacc[t] + w06 * l_row[t]; l_row[t] = 0.f; }
  }

  out[(size_t)(row0 + tm) * 65 + td] = ycur[tm][td];
  if (t < 16) out[(size_t)(row0 + t) * 65 + 64] = ld_row[t];
}

extern "C" void kernel_launch(void* const* d_in, const int* in_sizes, int n_in,
                              void* d_out, int out_size, void* d_ws, size_t ws_size,
                              hipStream_t stream) {
  (void)in_sizes; (void)n_in; (void)out_size; (void)ws_size;
  const float* x    = (const float*)d_in[0];
  const float* cond = (const float*)d_in[1];
  const float* eps  = (const float*)d_in[2];
  const float* W1   = (const float*)d_in[3];
  const float* b1   = (const float*)d_in[4];
  const float* W2   = (const float*)d_in[5];
  const float* b2   = (const float*)d_in[6];
  const float* W3   = (const float*)d_in[7];
  const float* b3   = (const float*)d_in[8];
  float* out = (float*)d_out;
  unsigned short* ws = (unsigned short*)d_ws;

  const int prep_total = 1343488;
  prep_bf16<<<(prep_total + 255) / 256, 256, 0, stream>>>(W1, W2, W3, ws);
  ffjord_mfma<<<256, 1024, 0, stream>>>(x, cond, eps, b1, b2, b3, ws, out);
}

// Round 6
// 2233.356 us; speedup vs baseline: 1.0385x; 1.0320x over previous
//
#include <hip/hip_runtime.h>

// FFJORD B=4096 D=64 C=16 H=512, NBIJ=2, NSTEPS=8 RK4 -> 64 sequential MLP+VJP evals.
// Round 12: R9-R11 falsified the allocator/spill family (unroll 4==8, waves_per_eu and
// LDS-pad all null; 29MB writes = 110 B/thread total, not a spill storm). Real issue:
// B-loads sit on the critical path (load->wait->MFMA, ~2000 cy/K-step) and the compiler
// never builds an async pipeline from HIP source. Fix: explicit 3-deep ring-buffered
// global_load_lds staging for GEMM2/GEMM4b B-panels (fire-and-forget, vmcnt-counted,
// zero VGPR load targets), bank-balanced XOR swizzle baked into the ws layout at prep
// (gload_lds writes linearly -> swizzle the SOURCE), per-wave slices so the ring needs
// no barriers. LDS 159.9KB: y-state moved to registers (thread-private), epsA folded
// into zA. Direct loads kept for the small GEMMs (1, 3f, 5b, e3).

typedef __attribute__((ext_vector_type(8))) short short8;
typedef __attribute__((ext_vector_type(4))) float f32x4;

#define MFMA_B16(a, b, c) __builtin_amdgcn_mfma_f32_16x16x32_bf16((a), (b), (c), 0, 0, 0)

__device__ __forceinline__ unsigned short f2bf(float f) {
  union { float f; unsigned u; } v; v.f = f;
  return (unsigned short)((v.u + 0x7FFFu + ((v.u >> 16) & 1u)) >> 16);
}
__device__ __forceinline__ float bf2f(unsigned short u) {
  union { unsigned u; float f; } v; v.u = ((unsigned)u) << 16; return v.f;
}
__device__ __forceinline__ float fast_tanh(float x) {
  float e = __expf(2.f * x);
  return 1.f - 2.f * __builtin_amdgcn_rcpf(e + 1.f);
}

// ws layout (ushort units), bf16:
// W1f  [2][512][96]      @ 0        column-major W1^T rows (k>=81 zero-padded)
// W2Fs [2][16][512][32]  @ 98304    staged W2^T: panel ks, row n, kk2; k = ks*32 + (kk2 ^ swz(n))
// W2Bs [2][16][512][32]  @ 622592   staged W2 (backward B), same panel/swizzle scheme
// W3f  [2][64][512]      @ 1146880  (W3^T: forward B)
// W3b  [2][512][64]      @ 1212416  (plain W3: B for e3 = eps@W3^T)
// W1y  [2][64][512]      @ 1277952  (first 64 rows of W1)
// swz(n) = ((n>>1)&3)<<3  -> balances ds_read_b128 across all 8 bank-quads.

__global__ void prep_bf16(const float* __restrict__ W1, const float* __restrict__ W2,
                          const float* __restrict__ W3, unsigned short* __restrict__ ws) {
  int o = blockIdx.x * 256 + threadIdx.x;
  if (o < 98304) {
    int ib = o / 49152, r = o % 49152, n = r / 96, k = r % 96;
    ws[o] = (k < 81) ? f2bf(W1[(size_t)ib * 41472 + k * 512 + n]) : (unsigned short)0;
  } else if (o < 622592) {
    int o2 = o - 98304;
    int ib = o2 / 262144, r = o2 % 262144;
    int ks = r / 16384, r2 = r % 16384;
    int n = r2 / 32, kk2 = r2 % 32;
    int k = ks * 32 + (kk2 ^ (((n >> 1) & 3) << 3));
    ws[o] = f2bf(W2[(size_t)ib * 262144 + k * 512 + n]);   // W2^T element (n,k)
  } else if (o < 1146880) {
    int o2 = o - 622592;
    int ib = o2 / 262144, r = o2 % 262144;
    int ks = r / 16384, r2 = r % 16384;
    int n = r2 / 32, kk2 = r2 % 32;
    int k = ks * 32 + (kk2 ^ (((n >> 1) & 3) << 3));
    ws[o] = f2bf(W2[(size_t)ib * 262144 + n * 512 + k]);   // W2 element (n,k)
  } else if (o < 1212416) {
    int o2 = o - 1146880;
    int ib = o2 / 32768, r = o2 % 32768, n = r / 512, k = r % 512;
    ws[o] = f2bf(W3[(size_t)ib * 32768 + k * 64 + n]);
  } else if (o < 1277952) {
    ws[o] = f2bf(W3[o - 1212416]);
  } else if (o < 1343488) {
    int o2 = o - 1277952;
    int ib = o2 / 32768, r = o2 % 32768, n = r / 512, k = r % 512;
    ws[o] = f2bf(W1[(size_t)ib * 41472 + n * 512 + k]);
  }
}

#define ZS 104   // z A-buffer stride (K=96 used; also hosts eps for the e3 GEMM)
#define HS 520   // h buffers stride (K=512)

// Per-wave async stage of one 2KB slice (32 rows) of a 32KB K-panel into the ring.
#define ISSUE_STAGE(WP, KS, BUF) do {                                                   \
    const unsigned short* _s = (WP) + (KS) * 16384 + (wave << 10) + (lane << 3);        \
    unsigned short* _d = &Bst[(BUF)][wave << 10];                                       \
    __builtin_amdgcn_global_load_lds(                                                   \
        (const __attribute__((address_space(1))) void*)_s,                              \
        (__attribute__((address_space(3))) void*)_d, 16, 0, 0);                         \
    __builtin_amdgcn_global_load_lds(                                                   \
        (const __attribute__((address_space(1))) void*)(_s + 512),                      \
        (__attribute__((address_space(3))) void*)(_d + 512), 16, 0, 0);                 \
  } while (0)

__global__ __launch_bounds__(1024) void ffjord_mfma(
    const float* __restrict__ x, const float* __restrict__ cond, const float* __restrict__ eps,
    const float* __restrict__ b1g, const float* __restrict__ b2g, const float* __restrict__ b3g,
    const unsigned short* __restrict__ ws, float* __restrict__ out) {
  __shared__ unsigned short zA[16 * ZS];
  __shared__ unsigned short h1A[16 * HS];     // h1; overwritten by g1 in GEMM4b
  __shared__ unsigned short h2A[16 * HS];
  __shared__ unsigned short g2A[16 * HS];
  __shared__ unsigned short Bst[3][16384];    // staging ring: 3 x 32KB K-panels
  __shared__ float eps_s[16][64];
  __shared__ float f_s[16][64];
  __shared__ float l_row[16], ld_row[16], ldacc[16];

  const int t = threadIdx.x;
  const int wave = t >> 6;
  const int lane = t & 63;
  const int lane15 = lane & 15;
  const int q8 = (lane >> 4) * 8;       // frag k-offset; C/D row base = q8>>1
  const int rowb = q8 >> 1;
  const int row0 = blockIdx.x * 16;
  const int ws32 = wave * 32;           // N-slice base for N=512 GEMMs
  const int nt3 = wave & 3;             // N-tile for N=64 GEMMs (3f, 5b)
  const int kb3 = (wave >> 2) * 128;    // K-slice base for N=64 GEMMs
  const int tm = t >> 6, td = t & 63;   // (row, dim) element owned by this thread

  // swizzled read offsets into a staged K-panel (ushort units), constant per thread
  const int kk2b = q8 ^ (((lane15 >> 1) & 3) << 3);
  const int boff0 = (ws32 + lane15) * 32 + kk2b;
  const int boff1 = boff0 + 512;        // +16 rows

  // RK4 state is thread-private: registers, not LDS
  float ycur, ytmp, yacc = 0.f;
  {
    float xv = x[(size_t)(row0 + tm) * 64 + td];
    ycur = xv; ytmp = xv;
  }
  if (t < 512) {
    int m = t >> 5, kk = t & 31;
    zA[m * ZS + 64 + kk] = (kk < 16) ? f2bf(cond[(size_t)(row0 + m) * 16 + kk]) : (unsigned short)0;
  }
  if (t < 16) { ld_row[t] = 0.f; l_row[t] = 0.f; }

  const float dt = 0.125f;
  const float w06 = dt / 6.f, w13 = dt / 3.f;

  for (int ib = 0; ib < 2; ++ib) {
    const unsigned short* W1f  = ws + 0       + ib * 49152;
    const unsigned short* W2fs = ws + 98304   + ib * 262144;
    const unsigned short* W2bs = ws + 622592  + ib * 262144;
    const unsigned short* W3f  = ws + 1146880 + ib * 32768;
    const unsigned short* W3b  = ws + 1212416 + ib * 32768;
    const unsigned short* W1y  = ws + 1277952 + ib * 32768;
    const float* b1b = b1g + ib * 512;
    const float* b2b = b2g + ib * 512;
    const float* b3b = b3g + ib * 64;

    // stage eps: f32 copy + bf16 A-tile (borrow zA; rewritten by P0 afterwards)
    {
      float ev = eps[((size_t)ib * 4096 + row0 + tm) * 64 + td];
      eps_s[tm][td] = ev;
      zA[tm * ZS + td] = f2bf(ev);
    }
    __syncthreads();

    // ---- e3 = eps @ W3^T (N=512, K=64), ONCE per bijector; kept in registers.
    float e3r[8];
    {
      f32x4 a0 = {0,0,0,0}, a1 = {0,0,0,0};
      const unsigned short* ap = zA + lane15 * ZS + q8;
      const unsigned short* wp = W3b + (size_t)(ws32 + lane15) * 64 + q8;
      #pragma unroll
      for (int kk = 0; kk < 64; kk += 32) {
        short8 a = *(const short8*)(ap + kk);
        a0 = MFMA_B16(a, *(const short8*)(wp + kk),           a0);
        a1 = MFMA_B16(a, *(const short8*)(wp + 16 * 64 + kk), a1);
      }
      #pragma unroll
      for (int rg = 0; rg < 4; ++rg) { e3r[rg] = a0[rg]; e3r[4 + rg] = a1[rg]; }
    }
    __syncthreads();   // zA about to be rewritten by P0

    for (int it = 0; it < 32; ++it) {
      const int s = it & 3;
      const float te = (it >> 2) * dt + ((s == 0) ? 0.f : (s == 3) ? dt : 0.5f * dt);

      // ---- P0: z build + zero f_s + deferred logdet + prefetch GEMM2 stages 0..2 ----
      zA[tm * ZS + td] = f2bf(ytmp);
      f_s[tm][td] = 0.f;
      if (t < 16) {
        if (it > 0) {
          int sp = (it - 1) & 3;
          float lv = l_row[t];
          if (sp == 0)      ldacc[t] = w06 * lv;
          else if (sp < 3)  ldacc[t] += w13 * lv;
          else              ld_row[t] += ldacc[t] + w06 * lv;
        }
        l_row[t] = 0.f;
        zA[t * ZS + 80] = f2bf(te);
      }
      ISSUE_STAGE(W2fs, 0, 0);
      ISSUE_STAGE(W2fs, 1, 1);
      ISSUE_STAGE(W2fs, 2, 2);
      __syncthreads();   // also drains the stage loads (compiler vmcnt(0) at barrier)

      // ---- P1: GEMM1: h1 = tanh(z @ W1 + b1), K=96, N=32/wave (direct loads) ----
      {
        f32x4 a0 = {0,0,0,0}, a1 = {0,0,0,0};
        const unsigned short* ap = zA + lane15 * ZS + q8;
        const unsigned short* wp = W1f + (size_t)(ws32 + lane15) * 96 + q8;
        #pragma unroll
        for (int k0 = 0; k0 < 96; k0 += 32) {
          short8 a = *(const short8*)(ap + k0);
          a0 = MFMA_B16(a, *(const short8*)(wp + k0),           a0);
          a1 = MFMA_B16(a, *(const short8*)(wp + 16 * 96 + k0), a1);
        }
        #pragma unroll
        for (int tl = 0; tl < 2; ++tl) {
          int n = ws32 + tl * 16 + lane15;
          float bias = b1b[n];
          f32x4 ac = tl ? a1 : a0;
          #pragma unroll
          for (int rg = 0; rg < 4; ++rg)
            h1A[(rowb + rg) * HS + n] = f2bf(fast_tanh(ac[rg] + bias));
        }
      }
      __syncthreads();

      // ---- P2: staged GEMM2: h2 = tanh(h1 @ W2 + b2); g2 fused in epilogue ----
      {
        f32x4 a0 = {0,0,0,0}, a1 = {0,0,0,0};
        const unsigned short* ap = h1A + lane15 * HS;
        #pragma unroll
        for (int ks = 0; ks < 16; ++ks) {
          if (ks < 14)       asm volatile("s_waitcnt vmcnt(4)" ::: "memory");
          else if (ks == 14) asm volatile("s_waitcnt vmcnt(2)" ::: "memory");
          else               asm volatile("s_waitcnt vmcnt(0)" ::: "memory");
          const unsigned short* bq = &Bst[ks % 3][0];
          short8 av = *(const short8*)(ap + ks * 32 + q8);
          short8 b0 = *(const short8*)(bq + boff0);
          short8 b1 = *(const short8*)(bq + boff1);
          asm volatile("s_waitcnt lgkmcnt(0)" ::: "memory");
          __builtin_amdgcn_sched_barrier(0);
          if (ks + 3 < 16) { ISSUE_STAGE(W2fs, ks + 3, (ks + 3) % 3); }
          a0 = MFMA_B16(av, b0, a0);
          a1 = MFMA_B16(av, b1, a1);
        }
        #pragma unroll
        for (int tl = 0; tl < 2; ++tl) {
          int n = ws32 + tl * 16 + lane15;
          float bias = b2b[n];
          f32x4 ac = tl ? a1 : a0;
          #pragma unroll
          for (int rg = 0; rg < 4; ++rg) {
            float h = fast_tanh(ac[rg] + bias);
            int off = (rowb + rg) * HS + n;
            h2A[off] = f2bf(h);
            g2A[off] = f2bf(e3r[tl * 4 + rg] * (1.f - h * h));
          }
        }
        // prefetch GEMM4b stages 0..2 (drained at the barrier below)
        ISSUE_STAGE(W2bs, 0, 0);
        ISSUE_STAGE(W2bs, 1, 1);
        ISSUE_STAGE(W2bs, 2, 2);
      }
      __syncthreads();

      // ---- P3: GEMM3f direct (f += h2 @ W3f) then staged GEMM4b ----
      {
        f32x4 c0 = {0,0,0,0};
        const unsigned short* ap3 = h2A + lane15 * HS + kb3 + q8;
        const unsigned short* wp3 = W3f + (size_t)(nt3 * 16 + lane15) * 512 + kb3 + q8;
        #pragma unroll
        for (int kk = 0; kk < 128; kk += 32)
          c0 = MFMA_B16(*(const short8*)(ap3 + kk), *(const short8*)(wp3 + kk), c0);
        #pragma unroll
        for (int rg = 0; rg < 4; ++rg)
          atomicAdd(&f_s[rowb + rg][nt3 * 16 + lane15], c0[rg]);
      }
      {
        f32x4 a0 = {0,0,0,0}, a1 = {0,0,0,0};
        const unsigned short* ap = g2A + lane15 * HS;
        #pragma unroll
        for (int ks = 0; ks < 16; ++ks) {
          if (ks < 14)       asm volatile("s_waitcnt vmcnt(4)" ::: "memory");
          else if (ks == 14) asm volatile("s_waitcnt vmcnt(2)" ::: "memory");
          else               asm volatile("s_waitcnt vmcnt(0)" ::: "memory");
          const unsigned short* bq = &Bst[ks % 3][0];
          short8 av = *(const short8*)(ap + ks * 32 + q8);
          short8 b0 = *(const short8*)(bq + boff0);
          short8 b1 = *(const short8*)(bq + boff1);
          asm volatile("s_waitcnt lgkmcnt(0)" ::: "memory");
          __builtin_amdgcn_sched_barrier(0);
          if (ks + 3 < 16) { ISSUE_STAGE(W2bs, ks + 3, (ks + 3) % 3); }
          a0 = MFMA_B16(av, b0, a0);
          a1 = MFMA_B16(av, b1, a1);
        }
        #pragma unroll
        for (int tl = 0; tl < 2; ++tl) {
          int n = ws32 + tl * 16 + lane15;
          f32x4 ac = tl ? a1 : a0;
          #pragma unroll
          for (int rg = 0; rg < 4; ++rg) {
            int off = (rowb + rg) * HS + n;
            float h = bf2f(h1A[off]);
            h1A[off] = f2bf(ac[rg] * (1.f - h * h));
          }
        }
      }
      __syncthreads();

      // ---- P4: GEMM5b direct (gz = g1 @ W1y^T, l = sum(gz*eps)) + RK4 update ----
      {
        f32x4 c0 = {0,0,0,0};
        const unsigned short* ap = h1A + lane15 * HS + kb3 + q8;
        const unsigned short* wp = W1y + (size_t)(nt3 * 16 + lane15) * 512 + kb3 + q8;
        #pragma unroll
        for (int kk = 0; kk < 128; kk += 32)
          c0 = MFMA_B16(*(const short8*)(ap + kk), *(const short8*)(wp + kk), c0);
        #pragma unroll
        for (int rg = 0; rg < 4; ++rg) {
          int m = rowb + rg;
          float p = c0[rg] * eps_s[m][nt3 * 16 + lane15];
          #pragma unroll
          for (int o = 1; o < 16; o <<= 1) p += __shfl_xor(p, o);
          if (lane15 == 0) atomicAdd(&l_row[m], p);
        }
      }
      {
        const float wk = (s == 0 || s == 3) ? w06 : w13;
        float fv = f_s[tm][td] + b3b[td];
        if (s == 0)      yacc = ycur + w06 * fv;
        else if (s < 3)  yacc += wk * fv;
        if (s < 3) {
          ytmp = ycur + ((s == 2) ? dt : 0.5f * dt) * fv;
        } else {
          float yn = yacc + w06 * fv;
          ycur = yn; ytmp = yn;
        }
      }
      __syncthreads();
    }

    // finalize deferred logdet stage for it=31 (stage 3)
    if (t < 16) { ld_row[t] += ldacc[t] + w06 * l_row[t]; l_row[t] = 0.f; }
    __syncthreads();
  }

  out[(size_t)(row0 + tm) * 65 + td] = ycur;
  if (t < 16) out[(size_t)(row0 + t) * 65 + 64] = ld_row[t];
}

extern "C" void kernel_launch(void* const* d_in, const int* in_sizes, int n_in,
                              void* d_out, int out_size, void* d_ws, size_t ws_size,
                              hipStream_t stream) {
  (void)in_sizes; (void)n_in; (void)out_size; (void)ws_size;
  const float* x    = (const float*)d_in[0];
  const float* cond = (const float*)d_in[1];
  const float* eps  = (const float*)d_in[2];
  const float* W1   = (const float*)d_in[3];
  const float* b1   = (const float*)d_in[4];
  const float* W2   = (const float*)d_in[5];
  const float* b2   = (const float*)d_in[6];
  const float* W3   = (const float*)d_in[7];
  const float* b3   = (const float*)d_in[8];
  float* out = (float*)d_out;
  unsigned short* ws = (unsigned short*)d_ws;

  const int prep_total = 1343488;
  prep_bf16<<<(prep_total + 255) / 256, 256, 0, stream>>>(W1, W2, W3, ws);
  ffjord_mfma<<<256, 1024, 0, stream>>>(x, cond, eps, b1, b2, b3, ws, out);
}

// Round 9
// 1451.833 us; speedup vs baseline: 1.5976x; 1.5383x over previous
//
#include <hip/hip_runtime.h>

// FFJORD B=4096 D=64 C=16 H=512, NBIJ=2, NSTEPS=8 RK4 -> 64 sequential MLP+VJP evals.
// Round 15: R14 failed absmax by 3% (0.4375 vs 0.425) - pure quant margin, machinery
// correct. Two precision recoveries at zero byte cost: (1) per-column W2 scales
// (prep_scales kernel computes exact col/row maxes; typical colmax 0.155 vs fixed 0.25
// -> 1.6x finer) folded into epilogues like the bias; (2) exact per-row g2 scale:
// g2 pre-quant kept in regs, shfl+atomicMax rowmax -> quantize after the barrier
// (+1 barrier/eval); removes the e3-headroom loss (~1.5-2x) on the logdet path.
// Theory under timing test (first datapoint): weight-byte-stream bound; i8 W2 cuts
// 1248 -> 736 KB/eval (-41%) => predict ~1550-1800us vs 2255 bf16.

typedef __attribute__((ext_vector_type(8))) short short8;
typedef __attribute__((ext_vector_type(4))) float f32x4;
typedef __attribute__((ext_vector_type(4))) int int4v;

#define MFMA_B16(a, b, c) __builtin_amdgcn_mfma_f32_16x16x32_bf16((a), (b), (c), 0, 0, 0)
#define MFMA_I8(a, b, c)  __builtin_amdgcn_mfma_i32_16x16x64_i8((a), (b), (c), 0, 0, 0)

__device__ __forceinline__ unsigned short f2bf(float f) {
  union { float f; unsigned u; } v; v.f = f;
  return (unsigned short)((v.u + 0x7FFFu + ((v.u >> 16) & 1u)) >> 16);
}
__device__ __forceinline__ float bf2f(unsigned short u) {
  union { unsigned u; float f; } v; v.u = ((unsigned)u) << 16; return v.f;
}
__device__ __forceinline__ float fast_tanh(float x) {
  float e = __expf(2.f * x);
  return 1.f - 2.f * __builtin_amdgcn_rcpf(e + 1.f);
}

// ws layout:
// W1f  bf16 [2][512][96]        @ ush 0       (k>=81 zero-padded)
// W2f8 i8   [2][8p][512n][64k]  @ byte 196608 (W2^T tiles; byte kk stores
//                                              k = p*64 + (kk ^ ((n>>1&3)<<4)))
// W2b8 i8   [2][8p][512r][64c]  @ byte 720896 (plain W2 tiles; byte c stores
//                                              col = p*64 + (c ^ ((r>>1&3)<<4)))
// W3f  bf16 [2][64][512]        @ ush 622592  (W3^T)
// W3b  bf16 [2][512][64]        @ ush 688128  (plain W3)
// W1y  bf16 [2][64][512]        @ ush 753664  (first 64 rows of W1)
// sc   f32  [2][2][512]         @ byte 1638400 (dir0: colmax_n |W2[:,n]| fwd;
//                                               dir1: rowmax_n |W2[n,:]| bwd)

__global__ void prep_scales(const float* __restrict__ W2, float* __restrict__ sc) {
  int idx = blockIdx.x * 256 + threadIdx.x;
  if (idx >= 2048) return;
  int ib = idx >> 10, dir = (idx >> 9) & 1, n = idx & 511;
  const float* W = W2 + (size_t)ib * 262144;
  float m = 0.f;
  if (dir == 0) { for (int k = 0; k < 512; ++k) m = fmaxf(m, fabsf(W[(size_t)k * 512 + n])); }
  else          { for (int k = 0; k < 512; ++k) m = fmaxf(m, fabsf(W[(size_t)n * 512 + k])); }
  sc[idx] = fmaxf(m, 1e-8f);
}

__global__ void prep_bf16(const float* __restrict__ W1, const float* __restrict__ W2,
                          const float* __restrict__ W3, unsigned short* __restrict__ ws) {
  int o = blockIdx.x * 256 + threadIdx.x;
  char* ws8 = (char*)ws;
  const float* sc = (const float*)(ws8 + 1638400);
  if (o < 98304) {
    int ib = o / 49152, r = o % 49152, n = r / 96, k = r % 96;
    ws[o] = (k < 81) ? f2bf(W1[(size_t)ib * 41472 + k * 512 + n]) : (unsigned short)0;
  } else if (o < 622592) {
    int b = o - 98304;
    int ib = b / 262144, b2 = b % 262144;
    int p = b2 / 32768, r2 = b2 % 32768, n = r2 / 64, kk = r2 & 63;
    int k = p * 64 + (kk ^ (((n >> 1) & 3) << 4));
    float w = W2[(size_t)ib * 262144 + (size_t)k * 512 + n];
    float s = sc[ib * 1024 + n];
    int q = (int)rintf(w * (127.f / s));
    q = q > 127 ? 127 : (q < -127 ? -127 : q);
    ws8[196608 + b] = (char)q;
  } else if (o < 1146880) {
    int b = o - 622592;
    int ib = b / 262144, b2 = b % 262144;
    int p = b2 / 32768, r2 = b2 % 32768, r = r2 / 64, c = r2 & 63;
    int col = p * 64 + (c ^ (((r >> 1) & 3) << 4));
    float w = W2[(size_t)ib * 262144 + (size_t)r * 512 + col];
    float s = sc[ib * 1024 + 512 + r];
    int q = (int)rintf(w * (127.f / s));
    q = q > 127 ? 127 : (q < -127 ? -127 : q);
    ws8[720896 + b] = (char)q;
  } else if (o < 1212416) {
    int o2 = o - 1146880;
    int ib = o2 / 32768, r = o2 % 32768, n = r / 512, k = r % 512;
    ws[622592 + o2] = f2bf(W3[(size_t)ib * 32768 + k * 64 + n]);
  } else if (o < 1277952) {
    int o2 = o - 1212416;
    ws[688128 + o2] = f2bf(W3[o2]);
  } else if (o < 1343488) {
    int o2 = o - 1277952;
    int ib = o2 / 32768, r = o2 % 32768, n = r / 512, k = r % 512;
    ws[753664 + o2] = f2bf(W1[(size_t)ib * 41472 + n * 512 + k]);
  }
}

#define ZS 104    // z A-buffer stride, ush (K=96 used; also hosts eps for the e3 GEMM)
#define HS 520    // bf16 h/g1 buffer stride, ush
#define H8 528    // i8 h1/g2 buffer stride, bytes
#define INV2 (1.f / 16129.f)   // 1/(127*127)

// Per-wave async stage of one 2KB slice (own 32 rows x 64 contraction bytes) of a
// 32KB i8 panel into the ring. LDS dest is wave-uniform; HW scatters lane*16.
#define ISSUE_STAGE(WP, KS, BUF) do {                                                   \
    const char* _s = (WP) + (KS) * 32768 + (wave << 11) + (lane << 4);                  \
    char* _d = &Bst[(BUF)][wave << 11];                                                 \
    __builtin_amdgcn_global_load_lds(                                                   \
        (const __attribute__((address_space(1))) void*)_s,                              \
        (__attribute__((address_space(3))) void*)_d, 16, 0, 0);                         \
    __builtin_amdgcn_global_load_lds(                                                   \
        (const __attribute__((address_space(1))) void*)(_s + 1024),                     \
        (__attribute__((address_space(3))) void*)(_d + 1024), 16, 0, 0);                \
  } while (0)

__global__ __launch_bounds__(1024) void ffjord_mfma(
    const float* __restrict__ x, const float* __restrict__ cond, const float* __restrict__ eps,
    const float* __restrict__ b1g, const float* __restrict__ b2g, const float* __restrict__ b3g,
    const unsigned short* __restrict__ ws, float* __restrict__ out) {
  __shared__ unsigned short zA[16 * ZS];
  __shared__ __align__(16) char h1A8[16 * H8];   // h1 as i8 (q = round(h1*127))
  __shared__ __align__(16) char g2A8[16 * H8];   // g2 as i8 (exact per-row scale)
  __shared__ unsigned short h2A[16 * HS];        // h2 bf16 (GEMM3f A-operand)
  __shared__ unsigned short g1A[16 * HS];        // g1 bf16 (GEMM5b A-operand)
  __shared__ __align__(16) char Bst[3][32768];   // staging ring: 3 x 32KB i8 panels
  __shared__ float eps_s[16][64];
  __shared__ float f_s[16][64];
  __shared__ float l_row[16], ld_row[16], ldacc[16];
  __shared__ int sgi2[16];                       // per-eval rowmax |g2| bits

  const int t = threadIdx.x;
  const int wave = t >> 6;
  const int lane = t & 63;
  const int lane15 = lane & 15;
  const int q8 = (lane >> 4) * 8;        // bf16 frag k-offset
  const int q16 = (lane >> 4) * 16;      // i8 frag k-offset (bytes)
  const int rowb = q8 >> 1;              // C/D row base
  const int row0 = blockIdx.x * 16;
  const int ws32 = wave * 32;            // N-slice base for N=512 GEMMs
  const int nt3 = wave & 3;              // N-tile for N=64 GEMMs (3f, 5b)
  const int kb3 = (wave >> 2) * 128;     // K-slice base for N=64 GEMMs
  const int tm = t >> 6, td = t & 63;    // (row, dim) element owned by this thread

  // swizzled 16B-granule read offset (same XOR for rows lane15 and 16+lane15)
  const int kk2b = q16 ^ (((lane15 >> 1) & 3) << 4);

  // RK4 state in registers (thread-private)
  float ycur, ytmp, yacc = 0.f;
  {
    float xv = x[(size_t)(row0 + tm) * 64 + td];
    ycur = xv; ytmp = xv;
  }
  if (t < 512) {
    int m = t >> 5, kk = t & 31;
    zA[m * ZS + 64 + kk] = (kk < 16) ? f2bf(cond[(size_t)(row0 + m) * 16 + kk]) : (unsigned short)0;
  }
  if (t < 16) { ld_row[t] = 0.f; l_row[t] = 0.f; }

  const float dt = 0.125f;
  const float w06 = dt / 6.f, w13 = dt / 3.f;
  const char* wsb = (const char*)ws;

  for (int ib = 0; ib < 2; ++ib) {
    const unsigned short* W1f = ws + ib * 49152;
    const char* W2f8 = wsb + 196608 + ib * 262144;
    const char* W2b8 = wsb + 720896 + ib * 262144;
    const unsigned short* W3f = ws + 622592 + ib * 32768;
    const unsigned short* W3b = ws + 688128 + ib * 32768;
    const unsigned short* W1y = ws + 753664 + ib * 32768;
    const float* scf = (const float*)(wsb + 1638400) + ib * 1024;  // fwd col scales
    const float* scb = scf + 512;                                  // bwd row scales
    const float* b1b = b1g + ib * 512;
    const float* b2b = b2g + ib * 512;
    const float* b3b = b3g + ib * 64;

    // stage eps: f32 copy + bf16 A-tile (borrow zA; rewritten by P0 afterwards)
    {
      float ev = eps[((size_t)ib * 4096 + row0 + tm) * 64 + td];
      eps_s[tm][td] = ev;
      zA[tm * ZS + td] = f2bf(ev);
    }
    __syncthreads();

    // ---- e3 = eps @ W3^T (N=512, K=64), ONCE per bijector; kept in registers.
    float e3r[8];
    {
      f32x4 a0 = {0,0,0,0}, a1 = {0,0,0,0};
      const unsigned short* ap = zA + lane15 * ZS + q8;
      const unsigned short* wp = W3b + (size_t)(ws32 + lane15) * 64 + q8;
      #pragma unroll
      for (int kk = 0; kk < 64; kk += 32) {
        short8 a = *(const short8*)(ap + kk);
        a0 = MFMA_B16(a, *(const short8*)(wp + kk),           a0);
        a1 = MFMA_B16(a, *(const short8*)(wp + 16 * 64 + kk), a1);
      }
      #pragma unroll
      for (int rg = 0; rg < 4; ++rg) { e3r[rg] = a0[rg]; e3r[4 + rg] = a1[rg]; }
    }
    __syncthreads();   // zA about to be rewritten by P0

    for (int it = 0; it < 32; ++it) {
      const int s = it & 3;
      const float te = (it >> 2) * dt + ((s == 0) ? 0.f : (s == 3) ? dt : 0.5f * dt);

      // ---- P0: z build + zero f_s/sgi2 + deferred logdet + prefetch fwd panels ----
      zA[tm * ZS + td] = f2bf(ytmp);
      f_s[tm][td] = 0.f;
      if (t < 16) {
        if (it > 0) {
          int sp = (it - 1) & 3;
          float lv = l_row[t];
          if (sp == 0)      ldacc[t] = w06 * lv;
          else if (sp < 3)  ldacc[t] += w13 * lv;
          else              ld_row[t] += ldacc[t] + w06 * lv;
        }
        l_row[t] = 0.f;
        sgi2[t] = 0;
        zA[t * ZS + 80] = f2bf(te);
      }
      ISSUE_STAGE(W2f8, 0, 0);
      ISSUE_STAGE(W2f8, 1, 1);
      ISSUE_STAGE(W2f8, 2, 2);
      __syncthreads();

      // ---- P1: GEMM1 (bf16): h1 = tanh(z @ W1 + b1), K=96; store h1 as i8 ----
      {
        f32x4 a0 = {0,0,0,0}, a1 = {0,0,0,0};
        const unsigned short* ap = zA + lane15 * ZS + q8;
        const unsigned short* wp = W1f + (size_t)(ws32 + lane15) * 96 + q8;
        #pragma unroll
        for (int k0 = 0; k0 < 96; k0 += 32) {
          short8 a = *(const short8*)(ap + k0);
          a0 = MFMA_B16(a, *(const short8*)(wp + k0),           a0);
          a1 = MFMA_B16(a, *(const short8*)(wp + 16 * 96 + k0), a1);
        }
        #pragma unroll
        for (int tl = 0; tl < 2; ++tl) {
          int n = ws32 + tl * 16 + lane15;
          float bias = b1b[n];
          f32x4 ac = tl ? a1 : a0;
          #pragma unroll
          for (int rg = 0; rg < 4; ++rg) {
            float th = fast_tanh(ac[rg] + bias);
            h1A8[(rowb + rg) * H8 + n] = (char)__float2int_rn(th * 127.f);
          }
        }
      }
      __syncthreads();

      // ---- P2: staged i8 GEMM2 -> h2 (per-col dequant); g2 pre-quant in regs ----
      float g2p[8];
      {
        int4v a0 = {0,0,0,0}, a1 = {0,0,0,0};
        const char* ap = h1A8 + lane15 * H8;
        #pragma unroll
        for (int ks = 0; ks < 8; ++ks) {
          if (ks < 6)       asm volatile("s_waitcnt vmcnt(4)" ::: "memory");
          else if (ks == 6) asm volatile("s_waitcnt vmcnt(2)" ::: "memory");
          else              asm volatile("s_waitcnt vmcnt(0)" ::: "memory");
          const char* bq = &Bst[ks % 3][wave << 11];
          int4v av = *(const int4v*)(ap + ks * 64 + q16);
          int4v b0 = *(const int4v*)(bq + lane15 * 64 + kk2b);
          int4v b1 = *(const int4v*)(bq + (16 + lane15) * 64 + kk2b);
          asm volatile("s_waitcnt lgkmcnt(0)" ::: "memory");
          __builtin_amdgcn_sched_barrier(0);
          if (ks + 3 < 8) { ISSUE_STAGE(W2f8, ks + 3, (ks + 3) % 3); }
          a0 = MFMA_I8(av, b0, a0);
          a1 = MFMA_I8(av, b1, a1);
        }
        #pragma unroll
        for (int tl = 0; tl < 2; ++tl) {
          int n = ws32 + tl * 16 + lane15;
          float bias = b2b[n];
          float dqn = scf[n] * INV2;
          int4v ac = tl ? a1 : a0;
          #pragma unroll
          for (int rg = 0; rg < 4; ++rg) {
            float h = fast_tanh((float)ac[rg] * dqn + bias);
            h2A[(rowb + rg) * HS + n] = f2bf(h);
            g2p[tl * 4 + rg] = e3r[tl * 4 + rg] * (1.f - h * h);
          }
        }
        // exact per-row max|g2|: reduce over the 16-lane quadrant, then cross-wave
        #pragma unroll
        for (int rg = 0; rg < 4; ++rg) {
          float mr = fmaxf(fabsf(g2p[rg]), fabsf(g2p[4 + rg]));
          #pragma unroll
          for (int o = 1; o < 16; o <<= 1) mr = fmaxf(mr, __shfl_xor(mr, o));
          if (lane15 == 0) atomicMax(&sgi2[rowb + rg], __float_as_int(mr));
        }
        // prefetch backward panels 0..2 (drained at the barrier below)
        ISSUE_STAGE(W2b8, 0, 0);
        ISSUE_STAGE(W2b8, 1, 1);
        ISSUE_STAGE(W2b8, 2, 2);
      }
      __syncthreads();

      // ---- P2b: quantize g2 with exact scale; GEMM3f (bf16 direct, f_s atomics) ----
      float dqg[4];
      {
        float qs2[4];
        #pragma unroll
        for (int rg = 0; rg < 4; ++rg) {
          float sg = fmaxf(__int_as_float(sgi2[rowb + rg]), 1e-20f);
          qs2[rg] = 127.f / sg;
          dqg[rg] = sg * INV2;
        }
        #pragma unroll
        for (int tl = 0; tl < 2; ++tl) {
          int n = ws32 + tl * 16 + lane15;
          #pragma unroll
          for (int rg = 0; rg < 4; ++rg)
            g2A8[(rowb + rg) * H8 + n] = (char)__float2int_rn(g2p[tl * 4 + rg] * qs2[rg]);
        }
      }
      {
        f32x4 c0 = {0,0,0,0};
        const unsigned short* ap3 = h2A + lane15 * HS + kb3 + q8;
        const unsigned short* wp3 = W3f + (size_t)(nt3 * 16 + lane15) * 512 + kb3 + q8;
        #pragma unroll
        for (int kk = 0; kk < 128; kk += 32)
          c0 = MFMA_B16(*(const short8*)(ap3 + kk), *(const short8*)(wp3 + kk), c0);
        #pragma unroll
        for (int rg = 0; rg < 4; ++rg)
          atomicAdd(&f_s[rowb + rg][nt3 * 16 + lane15], c0[rg]);
      }
      __syncthreads();

      // ---- P3: staged i8 GEMM4b -> g1A (bf16), per-row x per-col dequant ----
      {
        int4v a0 = {0,0,0,0}, a1 = {0,0,0,0};
        const char* ap = g2A8 + lane15 * H8;
        #pragma unroll
        for (int ks = 0; ks < 8; ++ks) {
          if (ks < 6)       asm volatile("s_waitcnt vmcnt(4)" ::: "memory");
          else if (ks == 6) asm volatile("s_waitcnt vmcnt(2)" ::: "memory");
          else              asm volatile("s_waitcnt vmcnt(0)" ::: "memory");
          const char* bq = &Bst[ks % 3][wave << 11];
          int4v av = *(const int4v*)(ap + ks * 64 + q16);
          int4v b0 = *(const int4v*)(bq + lane15 * 64 + kk2b);
          int4v b1 = *(const int4v*)(bq + (16 + lane15) * 64 + kk2b);
          asm volatile("s_waitcnt lgkmcnt(0)" ::: "memory");
          __builtin_amdgcn_sched_barrier(0);
          if (ks + 3 < 8) { ISSUE_STAGE(W2b8, ks + 3, (ks + 3) % 3); }
          a0 = MFMA_I8(av, b0, a0);
          a1 = MFMA_I8(av, b1, a1);
        }
        #pragma unroll
        for (int tl = 0; tl < 2; ++tl) {
          int n = ws32 + tl * 16 + lane15;
          float sbn = scb[n];
          int4v ac = tl ? a1 : a0;
          #pragma unroll
          for (int rg = 0; rg < 4; ++rg) {
            float pre = (float)ac[rg] * dqg[rg] * sbn;
            float h1v = (float)((signed char)h1A8[(rowb + rg) * H8 + n]) * (1.f / 127.f);
            g1A[(rowb + rg) * HS + n] = f2bf(pre * (1.f - h1v * h1v));
          }
        }
      }
      __syncthreads();

      // ---- P4: GEMM5b (bf16: gz = g1 @ W1y^T, l = sum(gz*eps)) + RK4 update ----
      {
        f32x4 c0 = {0,0,0,0};
        const unsigned short* ap = g1A + lane15 * HS + kb3 + q8;
        const unsigned short* wp = W1y + (size_t)(nt3 * 16 + lane15) * 512 + kb3 + q8;
        #pragma unroll
        for (int kk = 0; kk < 128; kk += 32)
          c0 = MFMA_B16(*(const short8*)(ap + kk), *(const short8*)(wp + kk), c0);
        #pragma unroll
        for (int rg = 0; rg < 4; ++rg) {
          int m = rowb + rg;
          float p = c0[rg] * eps_s[m][nt3 * 16 + lane15];
          #pragma unroll
          for (int o = 1; o < 16; o <<= 1) p += __shfl_xor(p, o);
          if (lane15 == 0) atomicAdd(&l_row[m], p);
        }
      }
      {
        const float wk = (s == 0 || s == 3) ? w06 : w13;
        float fv = f_s[tm][td] + b3b[td];
        if (s == 0)      yacc = ycur + w06 * fv;
        else if (s < 3)  yacc += wk * fv;
        if (s < 3) {
          ytmp = ycur + ((s == 2) ? dt : 0.5f * dt) * fv;
        } else {
          float yn = yacc + w06 * fv;
          ycur = yn; ytmp = yn;
        }
      }
      __syncthreads();
    }

    // finalize deferred logdet stage for it=31 (stage 3)
    if (t < 16) { ld_row[t] += ldacc[t] + w06 * l_row[t]; l_row[t] = 0.f; }
    __syncthreads();
  }

  out[(size_t)(row0 + tm) * 65 + td] = ycur;
  if (t < 16) out[(size_t)(row0 + t) * 65 + 64] = ld_row[t];
}

extern "C" void kernel_launch(void* const* d_in, const int* in_sizes, int n_in,
                              void* d_out, int out_size, void* d_ws, size_t ws_size,
                              hipStream_t stream) {
  (void)in_sizes; (void)n_in; (void)out_size; (void)ws_size;
  const float* x    = (const float*)d_in[0];
  const float* cond = (const float*)d_in[1];
  const float* eps  = (const float*)d_in[2];
  const float* W1   = (const float*)d_in[3];
  const float* b1   = (const float*)d_in[4];
  const float* W2   = (const float*)d_in[5];
  const float* b2   = (const float*)d_in[6];
  const float* W3   = (const float*)d_in[7];
  const float* b3   = (const float*)d_in[8];
  float* out = (float*)d_out;
  unsigned short* ws = (unsigned short*)d_ws;

  prep_scales<<<8, 256, 0, stream>>>(W2, (float*)((char*)ws + 1638400));
  const int prep_total = 1343488;
  prep_bf16<<<(prep_total + 255) / 256, 256, 0, stream>>>(W1, W2, W3, ws);
  ffjord_mfma<<<256, 1024, 0, stream>>>(x, cond, eps, b1, b2, b3, ws, out);
}

// Round 10
// 1064.136 us; speedup vs baseline: 2.1796x; 1.3643x over previous
//
#include <hip/hip_runtime.h>

// FFJORD B=4096 D=64 C=16 H=512, NBIJ=2, NSTEPS=8 RK4 -> 64 sequential MLP+VJP evals.
// Round 16: R15 confirmed time ~ weight-bytes/eval (stream x0.59 -> time x0.63).
// This round removes the entire backward-W2 stream algebraically:
//   l = sum(gz*eps) = sum_h g1_h u_h  with u = eps @ W1y   (ONCE per bijector)
//     = sum_n g2_n w_n with v = (1-h1^2) o u, w = v @ W2   (FORWARD orientation!)
// => GEMM4b/GEMM5b/W2b8/W1y-per-eval all deleted; w rides GEMM2's staged panels
// (2 extra MFMA/iter on shared B-frags); l completes in P2's epilogue (dot+shfl).
// g2 never quantized/stored (f32 regs). RK4 deferred into next P0 (logdet pattern).
// Eval = 4 phases: P0 | GEMM1 | dual-GEMM2 | GEMM3f. Next-eval panels prefetch at
// P3-start (latency hides under GEMM3f+P0). Stream 736 -> 416 KB/eval (-43%).

typedef __attribute__((ext_vector_type(8))) short short8;
typedef __attribute__((ext_vector_type(4))) float f32x4;
typedef __attribute__((ext_vector_type(4))) int int4v;

#define MFMA_B16(a, b, c) __builtin_amdgcn_mfma_f32_16x16x32_bf16((a), (b), (c), 0, 0, 0)
#define MFMA_I8(a, b, c)  __builtin_amdgcn_mfma_i32_16x16x64_i8((a), (b), (c), 0, 0, 0)

__device__ __forceinline__ unsigned short f2bf(float f) {
  union { float f; unsigned u; } v; v.f = f;
  return (unsigned short)((v.u + 0x7FFFu + ((v.u >> 16) & 1u)) >> 16);
}
__device__ __forceinline__ float bf2f(unsigned short u) {
  union { unsigned u; float f; } v; v.u = ((unsigned)u) << 16; return v.f;
}
__device__ __forceinline__ float fast_tanh(float x) {
  float e = __expf(2.f * x);
  return 1.f - 2.f * __builtin_amdgcn_rcpf(e + 1.f);
}

// ws layout:
// W1f  bf16 [2][512][96]       @ ush 0       (k>=81 zero-padded)
// W2f8 i8   [2][8p][512n][64k] @ byte 196608 (W2^T tiles; byte kk stores
//                                             k = p*64 + (kk ^ ((n>>1&3)<<4)))
// W3f  bf16 [2][64][512]       @ ush 360448  (W3^T: B for f = h2 @ W3)
// W3b  bf16 [2][512][64]       @ ush 425984  (plain W3: B for e3 = eps @ W3^T)
// W1u  bf16 [2][512][64]       @ ush 491520  (W1u[h][d] = W1[d][h]: B for u = eps @ W1y)
// sc   f32  [2][512]           @ byte 1114112 (colmax_n |W2[:,n]|)

__global__ void prep_scales(const float* __restrict__ W2, float* __restrict__ sc) {
  int idx = blockIdx.x * 256 + threadIdx.x;
  if (idx >= 1024) return;
  int ib = idx >> 9, n = idx & 511;
  const float* W = W2 + (size_t)ib * 262144;
  float m = 0.f;
  for (int k = 0; k < 512; ++k) m = fmaxf(m, fabsf(W[(size_t)k * 512 + n]));
  sc[idx] = fmaxf(m, 1e-8f);
}

__global__ void prep_bf16(const float* __restrict__ W1, const float* __restrict__ W2,
                          const float* __restrict__ W3, unsigned short* __restrict__ ws) {
  int o = blockIdx.x * 256 + threadIdx.x;
  char* ws8 = (char*)ws;
  const float* sc = (const float*)(ws8 + 1114112);
  if (o < 98304) {
    int ib = o / 49152, r = o % 49152, n = r / 96, k = r % 96;
    ws[o] = (k < 81) ? f2bf(W1[(size_t)ib * 41472 + k * 512 + n]) : (unsigned short)0;
  } else if (o < 622592) {
    int b = o - 98304;
    int ib = b / 262144, b2 = b % 262144;
    int p = b2 / 32768, r2 = b2 % 32768, n = r2 / 64, kk = r2 & 63;
    int k = p * 64 + (kk ^ (((n >> 1) & 3) << 4));
    float w = W2[(size_t)ib * 262144 + (size_t)k * 512 + n];
    float s = sc[ib * 512 + n];
    int q = (int)rintf(w * (127.f / s));
    q = q > 127 ? 127 : (q < -127 ? -127 : q);
    ws8[196608 + b] = (char)q;
  } else if (o < 688128) {
    int o2 = o - 622592;
    int ib = o2 / 32768, r = o2 % 32768, n = r / 512, k = r % 512;
    ws[360448 + o2] = f2bf(W3[(size_t)ib * 32768 + k * 64 + n]);
  } else if (o < 753664) {
    int o2 = o - 688128;
    ws[425984 + o2] = f2bf(W3[o2]);
  } else if (o < 819200) {
    int o2 = o - 753664;
    int ib = o2 / 32768, r = o2 % 32768, h = r / 64, d = r % 64;
    ws[491520 + o2] = f2bf(W1[(size_t)ib * 41472 + d * 512 + h]);
  }
}

#define ZS 104    // z A-buffer stride, ush (K=96 used; also hosts eps for e3/u GEMMs)
#define HS 520    // bf16 h2 buffer stride, ush
#define H8 528    // i8 h1/v buffer stride, bytes
#define INV2 (1.f / 16129.f)   // 1/(127*127)

// Per-wave async stage of one 2KB slice (own 32 rows x 64 bytes) of a 32KB i8 panel.
#define ISSUE_STAGE(WP, KS, BUF) do {                                                   \
    const char* _s = (WP) + (KS) * 32768 + (wave << 11) + (lane << 4);                  \
    char* _d = &Bst[(BUF)][wave << 11];                                                 \
    __builtin_amdgcn_global_load_lds(                                                   \
        (const __attribute__((address_space(1))) void*)_s,                              \
        (__attribute__((address_space(3))) void*)_d, 16, 0, 0);                         \
    __builtin_amdgcn_global_load_lds(                                                   \
        (const __attribute__((address_space(1))) void*)(_s + 1024),                     \
        (__attribute__((address_space(3))) void*)(_d + 1024), 16, 0, 0);                \
  } while (0)

__global__ __launch_bounds__(1024) void ffjord_mfma(
    const float* __restrict__ x, const float* __restrict__ cond, const float* __restrict__ eps,
    const float* __restrict__ b1g, const float* __restrict__ b2g, const float* __restrict__ b3g,
    const unsigned short* __restrict__ ws, float* __restrict__ out) {
  __shared__ unsigned short zA[16 * ZS];
  __shared__ __align__(16) char h1A8[16 * H8];   // h1 as i8 (q = round(h1*127))
  __shared__ __align__(16) char vA8[16 * H8];    // v = (1-h1^2)*u as i8 (scale su[m])
  __shared__ unsigned short h2A[16 * HS];        // h2 bf16 (GEMM3f A-operand)
  __shared__ __align__(16) char Bst[3][32768];   // staging ring: 3 x 32KB i8 panels
  __shared__ float f_s[16][64];
  __shared__ float l_row[16], ld_row[16], ldacc[16];
  __shared__ int sgu[16];                        // per-bijector rowmax |u| bits

  const int t = threadIdx.x;
  const int wave = t >> 6;
  const int lane = t & 63;
  const int lane15 = lane & 15;
  const int q8 = (lane >> 4) * 8;        // bf16 frag k-offset
  const int q16 = (lane >> 4) * 16;      // i8 frag k-offset (bytes)
  const int rowb = q8 >> 1;              // C/D row base
  const int row0 = blockIdx.x * 16;
  const int ws32 = wave * 32;            // N-slice base for N=512 GEMMs
  const int nt3 = wave & 3;              // N-tile for GEMM3f
  const int kb3 = (wave >> 2) * 128;     // K-slice base for GEMM3f
  const int tm = t >> 6, td = t & 63;    // (row, dim) element owned by this thread

  // swizzled 16B-granule read offset (same XOR for rows lane15 and 16+lane15)
  const int kk2b = q16 ^ (((lane15 >> 1) & 3) << 4);

  // RK4 state in registers (thread-private)
  float ycur, ytmp, yacc = 0.f;
  {
    float xv = x[(size_t)(row0 + tm) * 64 + td];
    ycur = xv; ytmp = xv;
  }
  if (t < 512) {
    int m = t >> 5, kk = t & 31;
    zA[m * ZS + 64 + kk] = (kk < 16) ? f2bf(cond[(size_t)(row0 + m) * 16 + kk]) : (unsigned short)0;
  }
  if (t < 16) { ld_row[t] = 0.f; l_row[t] = 0.f; }

  const float dt = 0.125f;
  const float w06 = dt / 6.f, w13 = dt / 3.f;
  const char* wsb = (const char*)ws;

  for (int ib = 0; ib < 2; ++ib) {
    const unsigned short* W1f = ws + ib * 49152;
    const char* W2f8 = wsb + 196608 + ib * 262144;
    const unsigned short* W3f = ws + 360448 + ib * 32768;
    const unsigned short* W3b = ws + 425984 + ib * 32768;
    const unsigned short* W1u = ws + 491520 + ib * 32768;
    const float* scf = (const float*)(wsb + 1114112) + ib * 512;
    const float* b1b = b1g + ib * 512;
    const float* b2b = b2g + ib * 512;
    const float* b3b = b3g + ib * 64;

    // ---- bijector prologue: stage eps (bf16, borrow zA), e3 + u GEMMs ----
    zA[tm * ZS + td] = f2bf(eps[((size_t)ib * 4096 + row0 + tm) * 64 + td]);
    if (t < 16) sgu[t] = 0;
    __syncthreads();

    float e3r[8], ur[8];
    {
      f32x4 a0 = {0,0,0,0}, a1 = {0,0,0,0};   // e3 = eps @ W3^T
      f32x4 u0 = {0,0,0,0}, u1 = {0,0,0,0};   // u  = eps @ W1y
      const unsigned short* ap = zA + lane15 * ZS + q8;
      const unsigned short* wp3 = W3b + (size_t)(ws32 + lane15) * 64 + q8;
      const unsigned short* wpu = W1u + (size_t)(ws32 + lane15) * 64 + q8;
      #pragma unroll
      for (int kk = 0; kk < 64; kk += 32) {
        short8 a = *(const short8*)(ap + kk);
        a0 = MFMA_B16(a, *(const short8*)(wp3 + kk),           a0);
        a1 = MFMA_B16(a, *(const short8*)(wp3 + 16 * 64 + kk), a1);
        u0 = MFMA_B16(a, *(const short8*)(wpu + kk),           u0);
        u1 = MFMA_B16(a, *(const short8*)(wpu + 16 * 64 + kk), u1);
      }
      #pragma unroll
      for (int rg = 0; rg < 4; ++rg) {
        e3r[rg] = a0[rg]; e3r[4 + rg] = a1[rg];
        ur[rg] = u0[rg];  ur[4 + rg] = u1[rg];
      }
      // per-row max|u| (exact per-bijector bound for the v quantization)
      #pragma unroll
      for (int rg = 0; rg < 4; ++rg) {
        float mr = fmaxf(fabsf(ur[rg]), fabsf(ur[4 + rg]));
        #pragma unroll
        for (int o = 1; o < 16; o <<= 1) mr = fmaxf(mr, __shfl_xor(mr, o));
        if (lane15 == 0) atomicMax(&sgu[rowb + rg], __float_as_int(mr));
      }
    }
    __syncthreads();   // sgu complete; zA about to be rewritten by P0

    float su_[4], qsv[4];
    #pragma unroll
    for (int rg = 0; rg < 4; ++rg) {
      float sg = fmaxf(__int_as_float(sgu[rowb + rg]), 1e-20f);
      su_[rg] = sg * INV2;       // folded w-dequant factor (x scf[n] later)
      qsv[rg] = 127.f / sg;
    }

    for (int it = 0; it < 32; ++it) {
      const int s = it & 3;
      const float te = (it >> 2) * dt + ((s == 0) ? 0.f : (s == 3) ? dt : 0.5f * dt);

      // ---- P0: deferred RK4 + logdet, z build, zero f_s; it==0: prefetch panels ----
      if (it > 0) {
        int sp = (it - 1) & 3;
        float fv = f_s[tm][td] + b3b[td];
        if (sp == 0)      { yacc = ycur + w06 * fv; ytmp = ycur + 0.5f * dt * fv; }
        else if (sp == 1) { yacc += w13 * fv;       ytmp = ycur + 0.5f * dt * fv; }
        else if (sp == 2) { yacc += w13 * fv;       ytmp = ycur + dt * fv; }
        else              { float yn = yacc + w06 * fv; ycur = yn; ytmp = yn; }
      }
      zA[tm * ZS + td] = f2bf(ytmp);
      f_s[tm][td] = 0.f;
      if (t < 16) {
        if (it > 0) {
          int sp = (it - 1) & 3;
          float lv = l_row[t];
          if (sp == 0)      ldacc[t] = w06 * lv;
          else if (sp < 3)  ldacc[t] += w13 * lv;
          else              ld_row[t] += ldacc[t] + w06 * lv;
        }
        l_row[t] = 0.f;
        zA[t * ZS + 80] = f2bf(te);
      }
      if (it == 0) { ISSUE_STAGE(W2f8, 0, 0); ISSUE_STAGE(W2f8, 1, 1); ISSUE_STAGE(W2f8, 2, 2); }
      __syncthreads();

      // ---- P1: GEMM1 (bf16): h1 = tanh(z @ W1 + b1); store h1 i8 and v i8 ----
      {
        f32x4 a0 = {0,0,0,0}, a1 = {0,0,0,0};
        const unsigned short* ap = zA + lane15 * ZS + q8;
        const unsigned short* wp = W1f + (size_t)(ws32 + lane15) * 96 + q8;
        #pragma unroll
        for (int k0 = 0; k0 < 96; k0 += 32) {
          short8 a = *(const short8*)(ap + k0);
          a0 = MFMA_B16(a, *(const short8*)(wp + k0),           a0);
          a1 = MFMA_B16(a, *(const short8*)(wp + 16 * 96 + k0), a1);
        }
        #pragma unroll
        for (int tl = 0; tl < 2; ++tl) {
          int n = ws32 + tl * 16 + lane15;
          float bias = b1b[n];
          f32x4 ac = tl ? a1 : a0;
          #pragma unroll
          for (int rg = 0; rg < 4; ++rg) {
            float th = fast_tanh(ac[rg] + bias);
            int off = (rowb + rg) * H8 + n;
            h1A8[off] = (char)__float2int_rn(th * 127.f);
            float v = (1.f - th * th) * ur[tl * 4 + rg];
            vA8[off] = (char)__float2int_rn(v * qsv[rg]);
          }
        }
      }
      __syncthreads();

      // ---- P2: staged dual i8 GEMM (h2-acc and w-acc share B-frags); l in epilogue ----
      {
        int4v ha0 = {0,0,0,0}, ha1 = {0,0,0,0}, wa0 = {0,0,0,0}, wa1 = {0,0,0,0};
        const char* aph = h1A8 + lane15 * H8;
        const char* apv = vA8 + lane15 * H8;
        #pragma unroll
        for (int ks = 0; ks < 8; ++ks) {
          if (ks < 6)       asm volatile("s_waitcnt vmcnt(4)" ::: "memory");
          else if (ks == 6) asm volatile("s_waitcnt vmcnt(2)" ::: "memory");
          else              asm volatile("s_waitcnt vmcnt(0)" ::: "memory");
          const char* bq = &Bst[ks % 3][wave << 11];
          int4v ah = *(const int4v*)(aph + ks * 64 + q16);
          int4v av = *(const int4v*)(apv + ks * 64 + q16);
          int4v b0 = *(const int4v*)(bq + lane15 * 64 + kk2b);
          int4v b1 = *(const int4v*)(bq + (16 + lane15) * 64 + kk2b);
          asm volatile("s_waitcnt lgkmcnt(0)" ::: "memory");
          __builtin_amdgcn_sched_barrier(0);
          if (ks + 3 < 8) { ISSUE_STAGE(W2f8, ks + 3, (ks + 3) % 3); }
          ha0 = MFMA_I8(ah, b0, ha0);
          ha1 = MFMA_I8(ah, b1, ha1);
          wa0 = MFMA_I8(av, b0, wa0);
          wa1 = MFMA_I8(av, b1, wa1);
        }
        float p0 = 0.f, p1 = 0.f, p2 = 0.f, p3 = 0.f;
        #pragma unroll
        for (int tl = 0; tl < 2; ++tl) {
          int n = ws32 + tl * 16 + lane15;
          float bias = b2b[n];
          float dq = scf[n] * INV2;
          float dqw = scf[n];
          int4v hac = tl ? ha1 : ha0;
          int4v wac = tl ? wa1 : wa0;
          #pragma unroll
          for (int rg = 0; rg < 4; ++rg) {
            float h = fast_tanh((float)hac[rg] * dq + bias);
            h2A[(rowb + rg) * HS + n] = f2bf(h);
            float g2 = e3r[tl * 4 + rg] * (1.f - h * h);
            float w = (float)wac[rg] * dqw * su_[rg];
            float pc = g2 * w;
            if (rg == 0) p0 += pc; else if (rg == 1) p1 += pc;
            else if (rg == 2) p2 += pc; else p3 += pc;
          }
        }
        #pragma unroll
        for (int o = 1; o < 16; o <<= 1) {
          p0 += __shfl_xor(p0, o); p1 += __shfl_xor(p1, o);
          p2 += __shfl_xor(p2, o); p3 += __shfl_xor(p3, o);
        }
        if (lane15 == 0) {
          atomicAdd(&l_row[rowb + 0], p0); atomicAdd(&l_row[rowb + 1], p1);
          atomicAdd(&l_row[rowb + 2], p2); atomicAdd(&l_row[rowb + 3], p3);
        }
      }
      __syncthreads();

      // ---- P3: prefetch next-eval panels; GEMM3f (bf16): f += h2 @ W3f ----
      if (it < 31) { ISSUE_STAGE(W2f8, 0, 0); ISSUE_STAGE(W2f8, 1, 1); ISSUE_STAGE(W2f8, 2, 2); }
      {
        f32x4 c0 = {0,0,0,0};
        const unsigned short* ap3 = h2A + lane15 * HS + kb3 + q8;
        const unsigned short* wp3 = W3f + (size_t)(nt3 * 16 + lane15) * 512 + kb3 + q8;
        #pragma unroll
        for (int kk = 0; kk < 128; kk += 32)
          c0 = MFMA_B16(*(const short8*)(ap3 + kk), *(const short8*)(wp3 + kk), c0);
        #pragma unroll
        for (int rg = 0; rg < 4; ++rg)
          atomicAdd(&f_s[rowb + rg][nt3 * 16 + lane15], c0[rg]);
      }
      __syncthreads();
    }

    // ---- bijector finalize: last RK4 stage (s=3) + logdet stage ----
    {
      float fv = f_s[tm][td] + b3b[td];
      float yn = yacc + w06 * fv;
      ycur = yn; ytmp = yn;
    }
    if (t < 16) { ld_row[t] += ldacc[t] + w06 * l_row[t]; l_row[t] = 0.f; }
    __syncthreads();
  }

  out[(size_t)(row0 + tm) * 65 + td] = ycur;
  if (t < 16) out[(size_t)(row0 + t) * 65 + 64] = ld_row[t];
}

extern "C" void kernel_launch(void* const* d_in, const int* in_sizes, int n_in,
                              void* d_out, int out_size, void* d_ws, size_t ws_size,
                              hipStream_t stream) {
  (void)in_sizes; (void)n_in; (void)out_size; (void)ws_size;
  const float* x    = (const float*)d_in[0];
  const float* cond = (const float*)d_in[1];
  const float* eps  = (const float*)d_in[2];
  const float* W1   = (const float*)d_in[3];
  const float* b1   = (const float*)d_in[4];
  const float* W2   = (const float*)d_in[5];
  const float* b2   = (const float*)d_in[6];
  const float* W3   = (const float*)d_in[7];
  const float* b3   = (const float*)d_in[8];
  float* out = (float*)d_out;
  unsigned short* ws = (unsigned short*)d_ws;

  prep_scales<<<4, 256, 0, stream>>>(W2, (float*)((char*)ws + 1114112));
  const int prep_total = 819200;
  prep_bf16<<<(prep_total + 255) / 256, 256, 0, stream>>>(W1, W2, W3, ws);
  ffjord_mfma<<<256, 1024, 0, stream>>>(x, cond, eps, b1, b2, b3, ws, out);
}